// Round 9
// baseline (682.087 us; speedup 1.0000x reference)
//
#include <hip/hip_runtime.h>
#include <hip/hip_bf16.h>

// Problem constants (fixed by setup_inputs)
#define TDIM 4096
#define BDIM 4
#define DDIM 1024
#define HDIM 16
#define HD   64
#define MDIM (TDIM * BDIM)      // 16384 rows (t,b)

typedef __attribute__((ext_vector_type(8))) short short8v;  // 8 bf16 bits = 4 VGPR
typedef __attribute__((ext_vector_type(4))) float f32x4;

__device__ __forceinline__ ushort f2bfu(float f) {
  union { __hip_bfloat16 h; ushort u; } c;
  c.h = __float2bfloat16(f);
  return c.u;
}
__device__ __forceinline__ float bfu2f(ushort u) {
  union { ushort u; __hip_bfloat16 h; } c;
  c.u = u;
  return __bfloat162float(c.h);
}

// async global->LDS, 16B per lane; LDS dest = wave-uniform base + lane*16
#define GLOAD16(gp, lp) __builtin_amdgcn_global_load_lds( \
    (const __attribute__((address_space(1))) void*)(gp),  \
    (__attribute__((address_space(3))) void*)(lp), 16, 0, 0)

// LDS swizzle: g(row) = (row>>1)&3 (r4-verified: BANK_CONFLICT 2.5e7 -> 0)
#define SWZ(row) (((row) >> 1) & 3)

// ---------------------------------------------------------------------------
// split fp32 -> bf16 hi/lo arrays (hi = bf16(x), lo = bf16(x - hi))
// ---------------------------------------------------------------------------
__global__ __launch_bounds__(256)
void split_f32(const float* __restrict__ in, ushort* __restrict__ hi,
               ushort* __restrict__ lo, int n4)
{
  int i = blockIdx.x * blockDim.x + threadIdx.x;
  const int stride = gridDim.x * blockDim.x;
  for (; i < n4; i += stride) {
    const float4 v = ((const float4*)in)[i];
    ushort4 h, l;
    h.x = f2bfu(v.x); l.x = f2bfu(v.x - bfu2f(h.x));
    h.y = f2bfu(v.y); l.y = f2bfu(v.y - bfu2f(h.y));
    h.z = f2bfu(v.z); l.z = f2bfu(v.z - bfu2f(h.z));
    h.w = f2bfu(v.w); l.w = f2bfu(v.w - bfu2f(h.w));
    ((ushort4*)hi)[i] = h;
    ((ushort4*)lo)[i] = l;
  }
}

// ---------------------------------------------------------------------------
// Wv transpose + split: WvT[d][e] = Wqkv[2048+e][d], bf16 hi/lo.
// 64x64 LDS tile per block, grid (16 d-tiles, 16 e-tiles).
// ---------------------------------------------------------------------------
__global__ __launch_bounds__(256)
void wvt_split(const float* __restrict__ Wqkv, ushort* __restrict__ WvTh,
               ushort* __restrict__ WvTl)
{
  __shared__ float ld[64][68];      // [e_local][d_local], padded
  const int d0 = blockIdx.x * 64, e0 = blockIdx.y * 64;
  const int tid = threadIdx.x;
  const int rr = tid >> 4, cc = tid & 15;
#pragma unroll
  for (int i = 0; i < 4; ++i) {
    const int el = rr + i * 16;
    const float4 v = *(const float4*)&Wqkv[(size_t)(2048 + e0 + el) * 1024 + d0 + cc * 4];
    ld[el][cc*4+0] = v.x; ld[el][cc*4+1] = v.y;
    ld[el][cc*4+2] = v.z; ld[el][cc*4+3] = v.w;
  }
  __syncthreads();
#pragma unroll
  for (int i = 0; i < 4; ++i) {
    const int dl = rr + i * 16;
    const float v0 = ld[cc*4+0][dl], v1 = ld[cc*4+1][dl];
    const float v2 = ld[cc*4+2][dl], v3 = ld[cc*4+3][dl];
    ushort4 h4, l4;
    h4.x = f2bfu(v0); l4.x = f2bfu(v0 - bfu2f(h4.x));
    h4.y = f2bfu(v1); l4.y = f2bfu(v1 - bfu2f(h4.y));
    h4.z = f2bfu(v2); l4.z = f2bfu(v2 - bfu2f(h4.z));
    h4.w = f2bfu(v3); l4.w = f2bfu(v3 - bfu2f(h4.w));
    const size_t o = (size_t)(d0 + dl) * 1024 + e0 + cc * 4;
    *(ushort4*)&WvTh[o] = h4;
    *(ushort4*)&WvTl[o] = l4;
  }
}

// ---------------------------------------------------------------------------
// GEMM1 (q,k only): [q|k] = x @ Wqk^T + b via split-bf16 3-MFMA.
// r6-proven structure: A = x fp32 reg-staged + split on the fly (co-issues
// with MFMA per m114/r7), B = pre-split via gload_lds, 2 barriers/K-step.
// Output: q -> Qc[bh][t][64] fp32 head-major; k -> Kc.
// 128x128 tile, BK=32, 4 waves (2x2), 48 MFMA/wave/iter.
// ---------------------------------------------------------------------------
__global__ __launch_bounds__(256, 2)
void gemm1_qk(const float* __restrict__ X, const ushort* __restrict__ Wh,
              const ushort* __restrict__ Wl, const float* __restrict__ bias,
              float* __restrict__ Qc, float* __restrict__ Kc)
{
  __shared__ ushort sAh[128][32], sAl[128][32], sBh[128][32], sBl[128][32];
  const int tid = threadIdx.x;
  const int lane = tid & 63, wid = tid >> 6;
  const int m0 = blockIdx.y * 128, n0 = blockIdx.x * 128;
  const int ar = tid >> 3, aq = tid & 7;
  const int wm = wid >> 1, wn = wid & 1;
  const int fr = lane & 15, kg = lane >> 4;

  f32x4 acc[4][4];
#pragma unroll
  for (int m = 0; m < 4; ++m)
#pragma unroll
    for (int n = 0; n < 4; ++n) acc[m][n] = (f32x4){0.f, 0.f, 0.f, 0.f};

  for (int k0 = 0; k0 < DDIM; k0 += 32) {
    float4 av[4];
#pragma unroll
    for (int i = 0; i < 4; ++i)
      av[i] = *(const float4*)&X[(size_t)(m0 + ar + i * 32) * DDIM + k0 + aq * 4];
#pragma unroll
    for (int j = 0; j < 4; ++j) {
      const int c = wid * 4 + j;                 // 16 chunks: 8 Bh + 8 Bl
      const int r0 = (c & 7) * 16;
      const int row = r0 + (lane >> 2);
      const int s = lane & 3;
      const size_t goff = (size_t)(n0 + row) * DDIM + k0 + ((s ^ SWZ(row)) << 3);
      if (c < 8) GLOAD16(Wh + goff, &sBh[r0][0]);
      else       GLOAD16(Wl + goff, &sBl[r0][0]);
    }
#pragma unroll
    for (int i = 0; i < 4; ++i) {
      const int row = ar + i * 32;
      const int sl = (((aq >> 1) ^ SWZ(row)) << 3) + ((aq & 1) << 2);
      ushort4 hv, lv;
      hv.x = f2bfu(av[i].x); lv.x = f2bfu(av[i].x - bfu2f(hv.x));
      hv.y = f2bfu(av[i].y); lv.y = f2bfu(av[i].y - bfu2f(hv.y));
      hv.z = f2bfu(av[i].z); lv.z = f2bfu(av[i].z - bfu2f(hv.z));
      hv.w = f2bfu(av[i].w); lv.w = f2bfu(av[i].w - bfu2f(hv.w));
      *(ushort4*)&sAh[row][sl] = hv;
      *(ushort4*)&sAl[row][sl] = lv;
    }
    __syncthreads();

    short8v ah[4], al[4], bh[4], bl[4];
#pragma unroll
    for (int m = 0; m < 4; ++m) {
      const int row = wm * 64 + m * 16 + fr;
      const int so = (kg ^ SWZ(row)) << 3;
      ah[m] = *(const short8v*)&sAh[row][so];
      al[m] = *(const short8v*)&sAl[row][so];
    }
#pragma unroll
    for (int n = 0; n < 4; ++n) {
      const int col = wn * 64 + n * 16 + fr;
      const int so = (kg ^ SWZ(col)) << 3;
      bh[n] = *(const short8v*)&sBh[col][so];
      bl[n] = *(const short8v*)&sBl[col][so];
    }
#pragma unroll
    for (int m = 0; m < 4; ++m)
#pragma unroll
      for (int n = 0; n < 4; ++n) {
        acc[m][n] = __builtin_amdgcn_mfma_f32_16x16x32_bf16(ah[m], bh[n], acc[m][n], 0, 0, 0);
        acc[m][n] = __builtin_amdgcn_mfma_f32_16x16x32_bf16(ah[m], bl[n], acc[m][n], 0, 0, 0);
        acc[m][n] = __builtin_amdgcn_mfma_f32_16x16x32_bf16(al[m], bh[n], acc[m][n], 0, 0, 0);
      }
    __syncthreads();
  }

  // epilogue: C/D layout col=lane&15, row=(lane>>4)*4+reg (m89)
  const int region = n0 >> 10;   // 0=q, 1=k
#pragma unroll
  for (int m = 0; m < 4; ++m)
#pragma unroll
    for (int n = 0; n < 4; ++n) {
      const int col = n0 + wn * 64 + n * 16 + fr;
      const float bz = bias[col];
      const int cc = col & 1023;
      const int hh = cc >> 6, dd = cc & 63;
#pragma unroll
      for (int r = 0; r < 4; ++r) {
        const int row = m0 + wm * 64 + m * 16 + kg * 4 + r;
        const float v = acc[m][n][r] + bz;
        const int t = row >> 2, b = row & 3;     // rows are (t,b) interleaved
        const size_t ho = (((size_t)(b * 16 + hh)) * 4096 + t) * 64 + dd;
        if (region == 0) Qc[ho] = v;
        else             Kc[ho] = v;
      }
    }
}

// ---------------------------------------------------------------------------
// Wfull_b = Weff_b @ Wv  (batched, hi/lo in, hi/lo out).
// C[n][d] = sum_e Weff_b[n][e] * WvT[d][e]. BM=64, BN=128, r6-gemm2 template.
// ---------------------------------------------------------------------------
__global__ __launch_bounds__(256, 2)
void wfull_mfma(const ushort* __restrict__ Aeh, const ushort* __restrict__ Ael,
                const ushort* __restrict__ Bth, const ushort* __restrict__ Btl,
                ushort* __restrict__ Wfh, ushort* __restrict__ Wfl)
{
  __shared__ ushort sAh[64][32], sAl[64][32], sBh[128][32], sBl[128][32];
  const int tid = threadIdx.x;
  const int lane = tid & 63, wid = tid >> 6;
  const int m0 = blockIdx.y * 64, n0 = blockIdx.x * 128, bb = blockIdx.z;
  const int wm = wid >> 1, wn = wid & 1;
  const int fr = lane & 15, kg = lane >> 4;

  f32x4 acc[2][4];
#pragma unroll
  for (int m = 0; m < 2; ++m)
#pragma unroll
    for (int n = 0; n < 4; ++n) acc[m][n] = (f32x4){0.f, 0.f, 0.f, 0.f};

  const size_t aB = (size_t)bb * 1048576;

  for (int k0 = 0; k0 < DDIM; k0 += 32) {
#pragma unroll
    for (int j = 0; j < 6; ++j) {
      const int c = wid * 6 + j;
      const int rl = lane >> 2, s = lane & 3;
      if (c < 8) {
        const int r0 = (c & 3) * 16;
        const int row = r0 + rl;
        const size_t g = aB + (size_t)(m0 + row) * 1024 + k0 + ((s ^ SWZ(row)) << 3);
        if (c < 4) GLOAD16(Aeh + g, &sAh[r0][0]);
        else       GLOAD16(Ael + g, &sAl[r0][0]);
      } else {
        const int r0 = ((c - 8) & 7) * 16;
        const int row = r0 + rl;
        const size_t g = (size_t)(n0 + row) * 1024 + k0 + ((s ^ SWZ(row)) << 3);
        if (c < 16) GLOAD16(Bth + g, &sBh[r0][0]);
        else        GLOAD16(Btl + g, &sBl[r0][0]);
      }
    }
    __syncthreads();

    short8v ah[2], al[2], bh[4], bl[4];
#pragma unroll
    for (int m = 0; m < 2; ++m) {
      const int row = wm * 32 + m * 16 + fr;
      const int so = (kg ^ SWZ(row)) << 3;
      ah[m] = *(const short8v*)&sAh[row][so];
      al[m] = *(const short8v*)&sAl[row][so];
    }
#pragma unroll
    for (int n = 0; n < 4; ++n) {
      const int col = wn * 64 + n * 16 + fr;
      const int so = (kg ^ SWZ(col)) << 3;
      bh[n] = *(const short8v*)&sBh[col][so];
      bl[n] = *(const short8v*)&sBl[col][so];
    }
#pragma unroll
    for (int m = 0; m < 2; ++m)
#pragma unroll
      for (int n = 0; n < 4; ++n) {
        acc[m][n] = __builtin_amdgcn_mfma_f32_16x16x32_bf16(ah[m], bh[n], acc[m][n], 0, 0, 0);
        acc[m][n] = __builtin_amdgcn_mfma_f32_16x16x32_bf16(ah[m], bl[n], acc[m][n], 0, 0, 0);
        acc[m][n] = __builtin_amdgcn_mfma_f32_16x16x32_bf16(al[m], bh[n], acc[m][n], 0, 0, 0);
      }
    __syncthreads();
  }

#pragma unroll
  for (int m = 0; m < 2; ++m)
#pragma unroll
    for (int n = 0; n < 4; ++n) {
      const int col = n0 + wn * 64 + n * 16 + fr;
#pragma unroll
      for (int r = 0; r < 4; ++r) {
        const int row = m0 + wm * 32 + m * 16 + kg * 4 + r;
        const float v = acc[m][n][r];
        const size_t o = aB + (size_t)row * 1024 + col;
        const ushort h2 = f2bfu(v);
        Wfh[o] = h2;
        Wfl[o] = f2bfu(v - bfu2f(h2));
      }
    }
}

// ---------------------------------------------------------------------------
// bias2[b][n] = sum_e Weff_b[n][e] * bv[e] + bout[n]   (bv = bqkv[2048:])
// ---------------------------------------------------------------------------
__global__ __launch_bounds__(256)
void bias2_kernel(const ushort* __restrict__ Weh, const ushort* __restrict__ Wel,
                  const float* __restrict__ bqkv, const float* __restrict__ bout,
                  float* __restrict__ bias2)
{
  __shared__ float bvs[1024];
  const int b = blockIdx.x, tid = threadIdx.x;
  *(float4*)&bvs[tid * 4] = *(const float4*)&bqkv[2048 + tid * 4];
  __syncthreads();
  const size_t base = (size_t)b * 1048576;
#pragma unroll
  for (int j = 0; j < 4; ++j) {
    const int n = tid + j * 256;
    const ushort* hr = Weh + base + (size_t)n * 1024;
    const ushort* lr = Wel + base + (size_t)n * 1024;
    float s = 0.f;
    for (int e = 0; e < 1024; e += 4) {
      const ushort4 h4 = *(const ushort4*)&hr[e];
      const ushort4 l4 = *(const ushort4*)&lr[e];
      s += (bfu2f(h4.x) + bfu2f(l4.x)) * bvs[e]
         + (bfu2f(h4.y) + bfu2f(l4.y)) * bvs[e + 1]
         + (bfu2f(h4.z) + bfu2f(l4.z)) * bvs[e + 2]
         + (bfu2f(h4.w) + bfu2f(l4.w)) * bvs[e + 3];
    }
    bias2[b * 1024 + n] = s + bout[n];
  }
}

// ---------------------------------------------------------------------------
// GEMM2x: out[t,b,:] = x[t,b,:] @ Wfull_b^T + bias2_b.  r6-gemm1 structure:
// A = x fp32 reg-staged + split on the fly, B = Wfull hi/lo via gload_lds.
// 128x128 tile, BK=32, grid (8, 32, 4).
// ---------------------------------------------------------------------------
__global__ __launch_bounds__(256, 2)
void gemm2x(const float* __restrict__ X, const ushort* __restrict__ Bh_,
            const ushort* __restrict__ Bl_, const float* __restrict__ bias2,
            float* __restrict__ Out)
{
  __shared__ ushort sAh[128][32], sAl[128][32], sBh[128][32], sBl[128][32];
  const int tid = threadIdx.x;
  const int lane = tid & 63, wid = tid >> 6;
  const int m0 = blockIdx.y * 128, n0 = blockIdx.x * 128, bb = blockIdx.z;
  const int ar = tid >> 3, aq = tid & 7;
  const int wm = wid >> 1, wn = wid & 1;
  const int fr = lane & 15, kg = lane >> 4;

  f32x4 acc[4][4];
#pragma unroll
  for (int m = 0; m < 4; ++m)
#pragma unroll
    for (int n = 0; n < 4; ++n) acc[m][n] = (f32x4){0.f, 0.f, 0.f, 0.f};

  const size_t wB = (size_t)bb * 1048576;

  for (int k0 = 0; k0 < DDIM; k0 += 32) {
    float4 av[4];
#pragma unroll
    for (int i = 0; i < 4; ++i)
      av[i] = *(const float4*)&X[((size_t)((m0 + ar + i * 32) * 4 + bb)) * 1024 + k0 + aq * 4];
#pragma unroll
    for (int j = 0; j < 4; ++j) {
      const int c = wid * 4 + j;
      const int r0 = (c & 7) * 16;
      const int row = r0 + (lane >> 2);
      const int s = lane & 3;
      const size_t goff = wB + (size_t)(n0 + row) * 1024 + k0 + ((s ^ SWZ(row)) << 3);
      if (c < 8) GLOAD16(Bh_ + goff, &sBh[r0][0]);
      else       GLOAD16(Bl_ + goff, &sBl[r0][0]);
    }
#pragma unroll
    for (int i = 0; i < 4; ++i) {
      const int row = ar + i * 32;
      const int sl = (((aq >> 1) ^ SWZ(row)) << 3) + ((aq & 1) << 2);
      ushort4 hv, lv;
      hv.x = f2bfu(av[i].x); lv.x = f2bfu(av[i].x - bfu2f(hv.x));
      hv.y = f2bfu(av[i].y); lv.y = f2bfu(av[i].y - bfu2f(hv.y));
      hv.z = f2bfu(av[i].z); lv.z = f2bfu(av[i].z - bfu2f(hv.z));
      hv.w = f2bfu(av[i].w); lv.w = f2bfu(av[i].w - bfu2f(hv.w));
      *(ushort4*)&sAh[row][sl] = hv;
      *(ushort4*)&sAl[row][sl] = lv;
    }
    __syncthreads();

    short8v ah[4], al[4], bh[4], bl[4];
#pragma unroll
    for (int m = 0; m < 4; ++m) {
      const int row = wm * 64 + m * 16 + fr;
      const int so = (kg ^ SWZ(row)) << 3;
      ah[m] = *(const short8v*)&sAh[row][so];
      al[m] = *(const short8v*)&sAl[row][so];
    }
#pragma unroll
    for (int n = 0; n < 4; ++n) {
      const int col = wn * 64 + n * 16 + fr;
      const int so = (kg ^ SWZ(col)) << 3;
      bh[n] = *(const short8v*)&sBh[col][so];
      bl[n] = *(const short8v*)&sBl[col][so];
    }
#pragma unroll
    for (int m = 0; m < 4; ++m)
#pragma unroll
      for (int n = 0; n < 4; ++n) {
        acc[m][n] = __builtin_amdgcn_mfma_f32_16x16x32_bf16(ah[m], bh[n], acc[m][n], 0, 0, 0);
        acc[m][n] = __builtin_amdgcn_mfma_f32_16x16x32_bf16(ah[m], bl[n], acc[m][n], 0, 0, 0);
        acc[m][n] = __builtin_amdgcn_mfma_f32_16x16x32_bf16(al[m], bh[n], acc[m][n], 0, 0, 0);
      }
    __syncthreads();
  }

  float* Ob = Out + (size_t)bb * 1024;    // row t -> offset t*4096
#pragma unroll
  for (int m = 0; m < 4; ++m)
#pragma unroll
    for (int n = 0; n < 4; ++n) {
      const int col = n0 + wn * 64 + n * 16 + fr;
      const float bz = bias2[bb * 1024 + col];
#pragma unroll
      for (int r = 0; r < 4; ++r) {
        const int row = m0 + wm * 64 + m * 16 + kg * 4 + r;
        Ob[(size_t)row * 4096 + col] = acc[m][n][r] + bz;
      }
    }
}

// ---------------------------------------------------------------------------
// Correlation partials (r6-proven): grid (64 bh, 16 seg), 4 waves, head-major
// streams, wave-private staging, barrier-free t-loop.
// ---------------------------------------------------------------------------
__global__ __launch_bounds__(256)
void corr_partial(const float* __restrict__ Qc, const float* __restrict__ Kc,
                  float* __restrict__ P)
{
  __shared__ float qs[4][16][64];
  __shared__ float ks[4][16][64];
  __shared__ float ssum[4][4][64];
  const int bh  = blockIdx.x;
  const int seg = blockIdx.y;
  const int tid = threadIdx.x;
  const int wid = tid >> 6, lane = tid & 63;
  const float* qb = Qc + (size_t)bh * 262144;
  const float* kb = Kc + (size_t)bh * 262144;
  const int ty = lane >> 3;
  const int tx = lane & 7;
  const int rr = lane >> 4;
  const int cq = lane & 15;

  float acc[8][8];
#pragma unroll
  for (int i = 0; i < 8; ++i)
#pragma unroll
    for (int j = 0; j < 8; ++j) acc[i][j] = 0.f;
  float sQ[4]  = {0,0,0,0}, sK[4]  = {0,0,0,0};
  float sQ2[4] = {0,0,0,0}, sK2[4] = {0,0,0,0};

  for (int c = 0; c < 4; ++c) {
    const int tbase = seg * 256 + wid * 64 + c * 16;
    float4 qv[4], kv[4];
#pragma unroll
    for (int i = 0; i < 4; ++i) {
      const size_t g = (size_t)(tbase + rr + i*4) * 64 + cq * 4;
      qv[i] = *(const float4*)&qb[g];
      kv[i] = *(const float4*)&kb[g];
    }
#pragma unroll
    for (int i = 0; i < 4; ++i) {
      const int row = rr + i*4;
      *(float4*)&qs[wid][row][cq*4] = qv[i];
      *(float4*)&ks[wid][row][cq*4] = kv[i];
      sQ[0] += qv[i].x; sQ[1] += qv[i].y; sQ[2] += qv[i].z; sQ[3] += qv[i].w;
      sK[0] += kv[i].x; sK[1] += kv[i].y; sK[2] += kv[i].z; sK[3] += kv[i].w;
      sQ2[0] = fmaf(qv[i].x, qv[i].x, sQ2[0]); sQ2[1] = fmaf(qv[i].y, qv[i].y, sQ2[1]);
      sQ2[2] = fmaf(qv[i].z, qv[i].z, sQ2[2]); sQ2[3] = fmaf(qv[i].w, qv[i].w, sQ2[3]);
      sK2[0] = fmaf(kv[i].x, kv[i].x, sK2[0]); sK2[1] = fmaf(kv[i].y, kv[i].y, sK2[1]);
      sK2[2] = fmaf(kv[i].z, kv[i].z, sK2[2]); sK2[3] = fmaf(kv[i].w, kv[i].w, sK2[3]);
    }
#pragma unroll 8
    for (int t = 0; t < 16; ++t) {
      const float4 qa  = *(const float4*)&qs[wid][t][ty*8];
      const float4 qb4 = *(const float4*)&qs[wid][t][ty*8+4];
      const float4 ka  = *(const float4*)&ks[wid][t][tx*8];
      const float4 kb4 = *(const float4*)&ks[wid][t][tx*8+4];
      const float av[8] = {qa.x, qa.y, qa.z, qa.w, qb4.x, qb4.y, qb4.z, qb4.w};
      const float bv[8] = {ka.x, ka.y, ka.z, ka.w, kb4.x, kb4.y, kb4.z, kb4.w};
#pragma unroll
      for (int i = 0; i < 8; ++i)
#pragma unroll
        for (int j = 0; j < 8; ++j)
          acc[i][j] = fmaf(av[i], bv[j], acc[i][j]);
    }
  }

#pragma unroll
  for (int j = 0; j < 4; ++j) {
    sQ[j]  += __shfl_xor(sQ[j], 16, 64);  sQ[j]  += __shfl_xor(sQ[j], 32, 64);
    sK[j]  += __shfl_xor(sK[j], 16, 64);  sK[j]  += __shfl_xor(sK[j], 32, 64);
    sQ2[j] += __shfl_xor(sQ2[j], 16, 64); sQ2[j] += __shfl_xor(sQ2[j], 32, 64);
    sK2[j] += __shfl_xor(sK2[j], 16, 64); sK2[j] += __shfl_xor(sK2[j], 32, 64);
  }
  if (lane < 16) {
    float4 q4; q4.x = sQ[0];  q4.y = sQ[1];  q4.z = sQ[2];  q4.w = sQ[3];
    float4 k4; k4.x = sK[0];  k4.y = sK[1];  k4.z = sK[2];  k4.w = sK[3];
    float4 q2; q2.x = sQ2[0]; q2.y = sQ2[1]; q2.z = sQ2[2]; q2.w = sQ2[3];
    float4 k2; k2.x = sK2[0]; k2.y = sK2[1]; k2.z = sK2[2]; k2.w = sK2[3];
    *(float4*)&ssum[wid][0][lane*4] = q4;
    *(float4*)&ssum[wid][1][lane*4] = k4;
    *(float4*)&ssum[wid][2][lane*4] = q2;
    *(float4*)&ssum[wid][3][lane*4] = k2;
  }

  float* cbuf = &qs[0][0][0];
  __syncthreads();
#pragma unroll
  for (int w = 0; w < 4; ++w) {
    if (wid == w) {
#pragma unroll
      for (int i = 0; i < 8; ++i) {
        float* p0 = &cbuf[(ty*8 + i) * 64 + tx*8];
        if (w == 0) {
          float4 o0, o1;
          o0.x = acc[i][0]; o0.y = acc[i][1]; o0.z = acc[i][2]; o0.w = acc[i][3];
          o1.x = acc[i][4]; o1.y = acc[i][5]; o1.z = acc[i][6]; o1.w = acc[i][7];
          *(float4*)p0 = o0; *(float4*)(p0 + 4) = o1;
        } else {
          float4 o0 = *(const float4*)p0, o1 = *(const float4*)(p0 + 4);
          o0.x += acc[i][0]; o0.y += acc[i][1]; o0.z += acc[i][2]; o0.w += acc[i][3];
          o1.x += acc[i][4]; o1.y += acc[i][5]; o1.z += acc[i][6]; o1.w += acc[i][7];
          *(float4*)p0 = o0; *(float4*)(p0 + 4) = o1;
        }
      }
    }
    __syncthreads();
  }

  float* Pb = P + (size_t)(bh * 16 + seg) * 4352;
#pragma unroll
  for (int i = 0; i < 4; ++i)
    ((float4*)Pb)[tid + 256*i] = ((const float4*)cbuf)[tid + 256*i];
  {
    const int comp = tid >> 6, d = tid & 63;
    Pb[4096 + tid] = ssum[0][comp][d] + ssum[1][comp][d] +
                     ssum[2][comp][d] + ssum[3][comp][d];
  }
}

// ---------------------------------------------------------------------------
// Finalize: corr = clip((c-SqSk/T)/sqrt(sx*sy),-1,1). grid (64 bh, 4 qtr).
// ---------------------------------------------------------------------------
__global__ __launch_bounds__(256)
void corr_finalize(const float* __restrict__ P, float* __restrict__ corr)
{
  __shared__ float fin[4][64];
  const int bh = blockIdx.x, qtr = blockIdx.y;
  const int tid = threadIdx.x;
  const float* Pb = P + (size_t)bh * 16 * 4352;

  float s = 0.f;
  for (int seg = 0; seg < 16; ++seg) s += Pb[(size_t)seg*4352 + 4096 + tid];
  fin[tid >> 6][tid & 63] = s;

  float cacc[4] = {0.f, 0.f, 0.f, 0.f};
  for (int seg = 0; seg < 16; ++seg) {
#pragma unroll
    for (int i = 0; i < 4; ++i)
      cacc[i] += Pb[(size_t)seg*4352 + qtr*1024 + tid + i*256];
  }
  __syncthreads();

  const float invT = 1.0f / (float)TDIM;
#pragma unroll
  for (int i = 0; i < 4; ++i) {
    const int f = qtr*1024 + tid + i*256;
    const int d = f >> 6, e = f & 63;
    const float sq = fin[0][d], sk = fin[1][e];
    const float sq2 = fin[2][d], sk2 = fin[3][e];
    const float cc = cacc[i] - sq * sk * invT;
    const float sx = sq2 - sq * sq * invT;
    const float sy = sk2 - sk * sk * invT;
    float v = cc / sqrtf(sx * sy);
    v = fminf(1.f, fmaxf(-1.f, v));
    corr[(size_t)bh * 4096 + f] = v;
  }
}

// ---------------------------------------------------------------------------
// Weff_b[n][h*64+d] = sum_e corr[b,h][d][e] * Wout[n][h*64+e] -> bf16 hi/lo
// ---------------------------------------------------------------------------
__global__ __launch_bounds__(256)
void weff_kernel(const float* __restrict__ corr, const float* __restrict__ Wout,
                 ushort* __restrict__ Weh, ushort* __restrict__ Wel)
{
  __shared__ float cs[64][64];
  __shared__ float ws[128][64];
  const int bh = blockIdx.x;
  const int b = bh >> 4, h = bh & 15;
  const int n0 = blockIdx.y * 128;
  const int tid = threadIdx.x;

  const float* cb = corr + (size_t)bh * 4096;
  float4* csv = (float4*)&cs[0][0];
#pragma unroll
  for (int i = 0; i < 4; ++i)
    csv[tid + 256*i] = ((const float4*)cb)[tid + 256*i];

  const int wr = tid >> 1, wh = (tid & 1) * 32;
  const float* wrow = Wout + (size_t)(n0 + wr) * DDIM + h * HD + wh;
#pragma unroll
  for (int i = 0; i < 8; ++i)
    *(float4*)&ws[wr][wh + i*4] = *(const float4*)&wrow[i*4];
  __syncthreads();

  const int ni = (tid >> 3) * 4;
  const int di = (tid & 7) * 8;
  float acc[4][8];
#pragma unroll
  for (int i = 0; i < 4; ++i)
#pragma unroll
    for (int j = 0; j < 8; ++j) acc[i][j] = 0.f;

  for (int e = 0; e < 64; ++e) {
    float wv[4], cv[8];
#pragma unroll
    for (int i = 0; i < 4; ++i) wv[i] = ws[ni + i][e];
#pragma unroll
    for (int j = 0; j < 8; ++j) cv[j] = cs[di + j][e];
#pragma unroll
    for (int i = 0; i < 4; ++i)
#pragma unroll
      for (int j = 0; j < 8; ++j)
        acc[i][j] = fmaf(wv[i], cv[j], acc[i][j]);
  }

  const size_t base = (size_t)b * DDIM * DDIM + h * HD;
#pragma unroll
  for (int i = 0; i < 4; ++i) {
    ushort4 h0, l0, h1, l1;
    h0.x = f2bfu(acc[i][0]); l0.x = f2bfu(acc[i][0] - bfu2f(h0.x));
    h0.y = f2bfu(acc[i][1]); l0.y = f2bfu(acc[i][1] - bfu2f(h0.y));
    h0.z = f2bfu(acc[i][2]); l0.z = f2bfu(acc[i][2] - bfu2f(h0.z));
    h0.w = f2bfu(acc[i][3]); l0.w = f2bfu(acc[i][3] - bfu2f(h0.w));
    h1.x = f2bfu(acc[i][4]); l1.x = f2bfu(acc[i][4] - bfu2f(h1.x));
    h1.y = f2bfu(acc[i][5]); l1.y = f2bfu(acc[i][5] - bfu2f(h1.y));
    h1.z = f2bfu(acc[i][6]); l1.z = f2bfu(acc[i][6] - bfu2f(h1.z));
    h1.w = f2bfu(acc[i][7]); l1.w = f2bfu(acc[i][7] - bfu2f(h1.w));
    const size_t o = base + (size_t)(n0 + ni + i) * DDIM + di;
    *(ushort4*)&Weh[o]     = h0;
    *(ushort4*)&Weh[o + 4] = h1;
    *(ushort4*)&Wel[o]     = l0;
    *(ushort4*)&Wel[o + 4] = l1;
  }
}

// ---------------------------------------------------------------------------
extern "C" void kernel_launch(void* const* d_in, const int* in_sizes, int n_in,
                              void* d_out, int out_size, void* d_ws, size_t ws_size,
                              hipStream_t stream)
{
  (void)in_sizes; (void)n_in; (void)out_size; (void)ws_size;
  const float* x    = (const float*)d_in[0];
  const float* Wqkv = (const float*)d_in[1];
  const float* bqkv = (const float*)d_in[2];
  const float* Wout = (const float*)d_in[3];
  const float* bout = (const float*)d_in[4];
  float* out = (float*)d_out;

  // ws layout (bytes), total 190,857,216 B = 182.0 MiB
  //  Qc, Kc  fp32 [64 bh][4096 t][64 d]  64+64 MiB
  //  corrB   fp32 [64][64][64]           1 MiB
  //  R1 17M: phase A Wqh/Wql (8.4M, qk rows only) -> phase B P (17M)
  //  Weh/Wel bf16 [4][1024][1024]        16 MiB
  //  WvTh/WvTl bf16 [1024][1024]         4 MiB
  //  Wfh/Wfl bf16 [4][1024][1024]        16 MiB
  //  bias2   fp32 [4][1024]              16 KiB
  char* w = (char*)d_ws;
  float*  Qc    = (float*)w;   w += (size_t)67108864;
  float*  Kc    = (float*)w;   w += (size_t)67108864;
  float*  corrB = (float*)w;   w += (size_t)1048576;
  char* R1 = w;                w += (size_t)17825792;
  ushort* Weh   = (ushort*)w;  w += (size_t)8388608;
  ushort* Wel   = (ushort*)w;  w += (size_t)8388608;
  ushort* WvTh  = (ushort*)w;  w += (size_t)2097152;
  ushort* WvTl  = (ushort*)w;  w += (size_t)2097152;
  ushort* Wfh   = (ushort*)w;  w += (size_t)8388608;
  ushort* Wfl   = (ushort*)w;  w += (size_t)8388608;
  float*  bias2 = (float*)w;   w += (size_t)16384;
  ushort* Wqh   = (ushort*)R1;
  ushort* Wql   = Wqh + (size_t)2097152;   // 2048 rows x 1024
  float*  P     = (float*)R1;

  // 1) split q,k rows of Wqkv -> bf16 hi/lo; transpose-split Wv
  split_f32<<<dim3(1024), 256, 0, stream>>>(Wqkv, Wqh, Wql, 524288);
  wvt_split<<<dim3(16, 16), 256, 0, stream>>>(Wqkv, WvTh, WvTl);
  // 2) q,k GEMM -> head-major fp32 Qc/Kc (V folded away)
  gemm1_qk<<<dim3(16, 128), 256, 0, stream>>>(x, Wqh, Wql, bqkv, Qc, Kc);
  // 3) correlation partials (P overwrites Wq splits - dead after GEMM1)
  corr_partial<<<dim3(64, 16), 256, 0, stream>>>(Qc, Kc, P);
  // 4) finalize corr
  corr_finalize<<<dim3(64, 4), 256, 0, stream>>>(P, corrB);
  // 5) Weff_b = fold(corr_b, Wout) -> bf16 hi/lo
  weff_kernel<<<dim3(64, 8), 256, 0, stream>>>(corrB, Wout, Weh, Wel);
  // 6) Wfull_b = Weff_b @ Wv -> bf16 hi/lo; bias2_b = Weff_b@bv + bout
  wfull_mfma<<<dim3(8, 16, 4), 256, 0, stream>>>(Weh, Wel, WvTh, WvTl, Wfh, Wfl);
  bias2_kernel<<<dim3(4), 256, 0, stream>>>(Weh, Wel, bqkv, bout, bias2);
  // 7) out = x @ Wfull_b^T + bias2_b (batched over b)
  gemm2x<<<dim3(8, 32, 4), 256, 0, stream>>>(x, Wfh, Wfl, bias2, out);
}